// Round 3
// baseline (98.401 us; speedup 1.0000x reference)
//
#include <hip/hip_runtime.h>
#include <hip/hip_bf16.h>

#define BB 2
#define TT 15
#define NN 2048
#define TO 8
#define MM 64
#define KH 32
#define DIMD 512
#define R2 0.49f

// ---------------- FPS v2: registers + coord-carrying butterfly + 1 barrier/iter ----------------
// one block per (b,f) frame; orig frame t = 2f
__global__ __launch_bounds__(256) void fps_kernel(const float* __restrict__ input,
                                                  float* __restrict__ anchor_xyz) {
    __shared__ float rv[2][4], rx[2][4], ry[2][4], rz[2][4];
    __shared__ int   ri[2][4];
    int blk = blockIdx.x;            // 0..15 = b*8+f
    int b = blk >> 3, f = blk & 7;
    const float* src = input + ((size_t)(b * TT + 2 * f)) * NN * 3;
    int tid = threadIdx.x, w = tid >> 6;

    // thread t owns consecutive points [8t, 8t+8) in registers
    float px[8], py[8], pz[8], mind[8];
    const float4* s4 = (const float4*)(src + tid * 24);
    float4 v0 = s4[0], v1 = s4[1], v2 = s4[2], v3 = s4[3], v4 = s4[4], v5 = s4[5];
    px[0] = v0.x; py[0] = v0.y; pz[0] = v0.z;
    px[1] = v0.w; py[1] = v1.x; pz[1] = v1.y;
    px[2] = v1.z; py[2] = v1.w; pz[2] = v2.x;
    px[3] = v2.y; py[3] = v2.z; pz[3] = v2.w;
    px[4] = v3.x; py[4] = v3.y; pz[4] = v3.z;
    px[5] = v3.w; py[5] = v4.x; pz[5] = v4.y;
    px[6] = v4.z; py[6] = v4.w; pz[6] = v5.x;
    px[7] = v5.y; py[7] = v5.z; pz[7] = v5.w;
#pragma unroll
    for (int j = 0; j < 8; ++j) mind[j] = 1e10f;

    // seed: point 0 (uniform scalar loads, broadcast)
    float lx = src[0], ly = src[1], lz = src[2];
    float* out = anchor_xyz + (size_t)blk * MM * 3;
    if (tid == 0) { out[0] = lx; out[1] = ly; out[2] = lz; }

    for (int it = 1; it < MM; ++it) {
        int pp = it & 1;
        float bv = -1.0f, bx = 0.f, by = 0.f, bz = 0.f;
        int bi = 1 << 30;
#pragma unroll
        for (int j = 0; j < 8; ++j) {
            float dx = px[j] - lx, dy = py[j] - ly, dz = pz[j] - lz;
            // no-FMA, fixed order: ((dx*dx + dy*dy) + dz*dz) to match numpy bitwise
            float d = __fadd_rn(__fadd_rn(__fmul_rn(dx, dx), __fmul_rn(dy, dy)),
                                __fmul_rn(dz, dz));
            float mv = fminf(mind[j], d);
            mind[j] = mv;
            // strict > + ascending j keeps numpy first-occurrence within thread
            if (mv > bv) { bv = mv; bi = tid * 8 + j; bx = px[j]; by = py[j]; bz = pz[j]; }
        }
        // wave butterfly argmax, carrying winner coords; first-index tie-break
#pragma unroll
        for (int off = 32; off >= 1; off >>= 1) {
            float ov = __shfl_xor(bv, off);
            int   oi = __shfl_xor(bi, off);
            float ox = __shfl_xor(bx, off);
            float oy = __shfl_xor(by, off);
            float oz = __shfl_xor(bz, off);
            if (ov > bv || (ov == bv && oi < bi)) { bv = ov; bi = oi; bx = ox; by = oy; bz = oz; }
        }
        if ((tid & 63) == 0) { rv[pp][w] = bv; ri[pp][w] = bi; rx[pp][w] = bx; ry[pp][w] = by; rz[pp][w] = bz; }
        __syncthreads();
        bv = rv[pp][0]; bi = ri[pp][0]; bx = rx[pp][0]; by = ry[pp][0]; bz = rz[pp][0];
#pragma unroll
        for (int ww = 1; ww < 4; ++ww) {
            float ov = rv[pp][ww]; int oi = ri[pp][ww];
            if (ov > bv || (ov == bv && oi < bi)) {
                bv = ov; bi = oi; bx = rx[pp][ww]; by = ry[pp][ww]; bz = rz[pp][ww];
            }
        }
        lx = bx; ly = by; lz = bz;   // block-uniform winner coords
        if (tid == 0) { out[it * 3 + 0] = lx; out[it * 3 + 1] = ly; out[it * 3 + 2] = lz; }
        // no second barrier: ping-pong buffer handles WAR across iterations
    }
}

// ---------------- Encode: one block per anchor (b,f,m); 256 threads = 2 dims each ----------------
__global__ __launch_bounds__(256) void encode_kernel(const float* __restrict__ input,
                                                     const float* __restrict__ W_d,
                                                     const float* __restrict__ W_f,
                                                     const float* __restrict__ W_pos,
                                                     const float* __restrict__ b_pos,
                                                     const float* __restrict__ anchor_xyz,
                                                     float* __restrict__ outp) {
    __shared__ float hx[KH], hy[KH], hz[KH];
    __shared__ int swtot[4];
    int bid = blockIdx.x;                 // b*512 + f*64 + m
    int b = bid >> 9;
    int rem = bid & 511;
    int f = rem >> 6;
    int m = rem & 63;
    int tid = threadIdx.x, lane = tid & 63, w = tid >> 6;

    const float* anc = anchor_xyz + (size_t)(((b << 3) + f) * MM + m) * 3;
    float ax = anc[0], ay = anc[1], az = anc[2];

    int d0 = tid, d1 = tid + 256;
    float4 wd0 = ((const float4*)W_d)[d0];
    float4 wd1 = ((const float4*)W_d)[d1];
    float  wf0 = W_f[d0], wf1 = W_f[d1];
    float p0 = -INFINITY, p1 = -INFINITY;

    for (int dt = -1; dt <= 1; ++dt) {
        int frame = 2 * f + dt;
        frame = frame < 0 ? 0 : (frame > 14 ? 14 : frame);
        const float* src = input + ((size_t)(b * TT + frame)) * NN * 3;

        // thread t owns consecutive points [8t, 8t+8)
        float px[8], py[8], pz[8];
        const float4* s4 = (const float4*)(src + tid * 24);
        float4 v0 = s4[0], v1 = s4[1], v2 = s4[2], v3 = s4[3], v4 = s4[4], v5 = s4[5];
        px[0] = v0.x; py[0] = v0.y; pz[0] = v0.z;
        px[1] = v0.w; py[1] = v1.x; pz[1] = v1.y;
        px[2] = v1.z; py[2] = v1.w; pz[2] = v2.x;
        px[3] = v2.y; py[3] = v2.z; pz[3] = v2.w;
        px[4] = v3.x; py[4] = v3.y; pz[4] = v3.z;
        px[5] = v3.w; py[5] = v4.x; pz[5] = v4.y;
        px[6] = v4.z; py[6] = v4.w; pz[6] = v5.x;
        px[7] = v5.y; py[7] = v5.z; pz[7] = v5.w;

        unsigned hit = 0; int cnt = 0;
#pragma unroll
        for (int j = 0; j < 8; ++j) {
            float dx = ax - px[j], dy = ay - py[j], dz = az - pz[j];
            float d2 = __fadd_rn(__fadd_rn(__fmul_rn(dx, dx), __fmul_rn(dy, dy)),
                                 __fmul_rn(dz, dz));
            if (d2 < R2) { hit |= 1u << j; cnt++; }
        }
        // wave inclusive scan of cnt
        int s = cnt;
#pragma unroll
        for (int off = 1; off < 64; off <<= 1) {
            int o = __shfl_up(s, off);
            if (lane >= off) s += o;
        }
        if (lane == 63) swtot[w] = s;
        __syncthreads();
        int wavebase = 0, total = 0;
#pragma unroll
        for (int ww = 0; ww < 4; ++ww) {
            int t2 = swtot[ww];
            total += t2;
            if (ww < w) wavebase += t2;
        }
        int r = wavebase + s - cnt;   // exclusive global rank of this thread's first hit
#pragma unroll
        for (int j = 0; j < 8; ++j) {
            if (hit & (1u << j)) {
                if (r < KH) { hx[r] = px[j]; hy[r] = py[j]; hz[r] = pz[j]; }
                r++;
            }
        }
        if (total == 0 && tid == 0) { hx[0] = px[0]; hy[0] = py[0]; hz[0] = pz[0]; }
        __syncthreads();

        int nh = (total == 0) ? 1 : (total < KH ? total : KH);
        float dtf = (float)dt;
        for (int k = 0; k < nh; ++k) {
            float gx = hx[k], gy = hy[k], gz = hz[k];
            float dx = gx - ax, dy = gy - ay, dz = gz - az;
            float v0d = dx * wd0.x + dy * wd0.y + dz * wd0.z + dtf * wd0.w + gz * wf0;
            float v1d = dx * wd1.x + dy * wd1.y + dz * wd1.z + dtf * wd1.w + gz * wf1;
            p0 = fmaxf(p0, v0d);
            p1 = fmaxf(p1, v1d);
        }
        __syncthreads();   // WAR on hx/hy/hz/swtot before next dt
    }

    // epilogue: positional linear + bias + relu, float32 store
    float4 wp0 = ((const float4*)W_pos)[d0];
    float4 wp1 = ((const float4*)W_pos)[d1];
    float tv = (float)(f + 1);
    float pos0 = ax * wp0.x + ay * wp0.y + az * wp0.z + tv * wp0.w + b_pos[d0];
    float pos1 = ax * wp1.x + ay * wp1.y + az * wp1.z + tv * wp1.w + b_pos[d1];
    float o0 = fmaxf(pos0 + p0, 0.0f);
    float o1 = fmaxf(pos1 + p1, 0.0f);
    size_t row = ((size_t)b * (TO * MM) + f * MM + m) * DIMD;
    outp[row + d0] = o0;
    outp[row + d1] = o1;
}

extern "C" void kernel_launch(void* const* d_in, const int* in_sizes, int n_in,
                              void* d_out, int out_size, void* d_ws, size_t ws_size,
                              hipStream_t stream) {
    const float* input = (const float*)d_in[0];
    const float* W_d   = (const float*)d_in[1];
    const float* W_f   = (const float*)d_in[2];
    const float* W_pos = (const float*)d_in[3];
    const float* b_pos = (const float*)d_in[4];
    float* anchor = (float*)d_ws;   // 16*64*3 floats = 12 KB

    fps_kernel<<<16, 256, 0, stream>>>(input, anchor);
    encode_kernel<<<1024, 256, 0, stream>>>(input, W_d, W_f, W_pos, b_pos, anchor,
                                            (float*)d_out);
}

// Round 4
// 86.777 us; speedup vs baseline: 1.1339x; 1.1339x over previous
//
#include <hip/hip_runtime.h>
#include <hip/hip_bf16.h>

#define BB 2
#define TT 15
#define NN 2048
#define TO 8
#define MM 64
#define KH 32
#define DIMD 512
#define R2 0.49f

// DPP cross-lane helpers (VALU, ~4cy — replaces ds_bpermute ~130cy)
template<int CTRL>
__device__ __forceinline__ float dppf(float x) {
    return __int_as_float(__builtin_amdgcn_update_dpp(
        __float_as_int(x), __float_as_int(x), CTRL, 0xF, 0xF, false));
}
template<int CTRL>
__device__ __forceinline__ int dppi(int x) {
    return __builtin_amdgcn_update_dpp(x, x, CTRL, 0xF, 0xF, false);
}

// ---------------- FPS v3: register points + DPP wave argmax ----------------
// one block per (b,f) frame; orig frame t = 2f
__global__ __launch_bounds__(256) void fps_kernel(const float* __restrict__ input,
                                                  float* __restrict__ anchor_xyz) {
    __shared__ float rv[2][4], rx[2][4], ry[2][4], rz[2][4];
    __shared__ int   ri[2][4];
    int blk = blockIdx.x;            // 0..15 = b*8+f
    int b = blk >> 3, f = blk & 7;
    const float* src = input + ((size_t)(b * TT + 2 * f)) * NN * 3;
    int tid = threadIdx.x, w = tid >> 6;

    // thread t owns consecutive points [8t, 8t+8) in registers
    float px[8], py[8], pz[8], mind[8];
    const float4* s4 = (const float4*)(src + tid * 24);
    float4 v0 = s4[0], v1 = s4[1], v2 = s4[2], v3 = s4[3], v4 = s4[4], v5 = s4[5];
    px[0] = v0.x; py[0] = v0.y; pz[0] = v0.z;
    px[1] = v0.w; py[1] = v1.x; pz[1] = v1.y;
    px[2] = v1.z; py[2] = v1.w; pz[2] = v2.x;
    px[3] = v2.y; py[3] = v2.z; pz[3] = v2.w;
    px[4] = v3.x; py[4] = v3.y; pz[4] = v3.z;
    px[5] = v3.w; py[5] = v4.x; pz[5] = v4.y;
    px[6] = v4.z; py[6] = v4.w; pz[6] = v5.x;
    px[7] = v5.y; py[7] = v5.z; pz[7] = v5.w;
#pragma unroll
    for (int j = 0; j < 8; ++j) mind[j] = 1e10f;

    // seed: point 0 (uniform scalar loads, broadcast)
    float lx = src[0], ly = src[1], lz = src[2];
    float* out = anchor_xyz + (size_t)blk * MM * 3;
    if (tid == 0) { out[0] = lx; out[1] = ly; out[2] = lz; }

    for (int it = 1; it < MM; ++it) {
        int pp = it & 1;
        float bv = -1.0f, bx = 0.f, by = 0.f, bz = 0.f;
        int bi = 1 << 30;
#pragma unroll
        for (int j = 0; j < 8; ++j) {
            float dx = px[j] - lx, dy = py[j] - ly, dz = pz[j] - lz;
            // no-FMA, fixed order: ((dx*dx + dy*dy) + dz*dz) to match numpy bitwise
            float d = __fadd_rn(__fadd_rn(__fmul_rn(dx, dx), __fmul_rn(dy, dy)),
                                __fmul_rn(dz, dz));
            float mv = fminf(mind[j], d);
            mind[j] = mv;
            // strict > + ascending j keeps numpy first-occurrence within thread
            if (mv > bv) { bv = mv; bi = tid * 8 + j; bx = px[j]; by = py[j]; bz = pz[j]; }
        }
        // wave argmax via DPP (VALU pipe): result lands in lane 63.
        // (max v, tie -> min i) is associative+commutative, so tree order is safe.
#define DPP_STEP(CTRL) { \
            float ov = dppf<CTRL>(bv); int oi = dppi<CTRL>(bi); \
            float ox = dppf<CTRL>(bx), oy = dppf<CTRL>(by), oz = dppf<CTRL>(bz); \
            bool t = (ov > bv) || (ov == bv && oi < bi); \
            bv = t ? ov : bv; bi = t ? oi : bi; \
            bx = t ? ox : bx; by = t ? oy : by; bz = t ? oz : bz; }
        DPP_STEP(0xB1)   // quad_perm xor1
        DPP_STEP(0x4E)   // quad_perm xor2
        DPP_STEP(0x141)  // row_half_mirror (within 8)
        DPP_STEP(0x140)  // row_mirror (within 16)
        DPP_STEP(0x142)  // row_bcast15: row r -> r+1
        DPP_STEP(0x143)  // row_bcast31: lane31 -> lanes 32..63
#undef DPP_STEP
        if ((tid & 63) == 63) { rv[pp][w] = bv; ri[pp][w] = bi; rx[pp][w] = bx; ry[pp][w] = by; rz[pp][w] = bz; }
        __syncthreads();
        bv = rv[pp][0]; bi = ri[pp][0]; bx = rx[pp][0]; by = ry[pp][0]; bz = rz[pp][0];
#pragma unroll
        for (int ww = 1; ww < 4; ++ww) {
            float ov = rv[pp][ww]; int oi = ri[pp][ww];
            if (ov > bv || (ov == bv && oi < bi)) {
                bv = ov; bi = oi; bx = rx[pp][ww]; by = ry[pp][ww]; bz = rz[pp][ww];
            }
        }
        lx = bx; ly = by; lz = bz;   // block-uniform winner coords
        if (tid == 0) { out[it * 3 + 0] = lx; out[it * 3 + 1] = ly; out[it * 3 + 2] = lz; }
        // no second barrier: ping-pong buffer handles WAR across iterations
    }
}

// ---------------- Encode: one block per anchor (b,f,m); 256 threads = 2 dims each ----------------
__global__ __launch_bounds__(256) void encode_kernel(const float* __restrict__ input,
                                                     const float* __restrict__ W_d,
                                                     const float* __restrict__ W_f,
                                                     const float* __restrict__ W_pos,
                                                     const float* __restrict__ b_pos,
                                                     const float* __restrict__ anchor_xyz,
                                                     float* __restrict__ outp) {
    __shared__ float hx[KH], hy[KH], hz[KH];
    __shared__ int swtot[4];
    int bid = blockIdx.x;                 // b*512 + f*64 + m
    int b = bid >> 9;
    int rem = bid & 511;
    int f = rem >> 6;
    int m = rem & 63;
    int tid = threadIdx.x, lane = tid & 63, w = tid >> 6;

    const float* anc = anchor_xyz + (size_t)(((b << 3) + f) * MM + m) * 3;
    float ax = anc[0], ay = anc[1], az = anc[2];

    int d0 = tid, d1 = tid + 256;
    float4 wd0 = ((const float4*)W_d)[d0];
    float4 wd1 = ((const float4*)W_d)[d1];
    float  wf0 = W_f[d0], wf1 = W_f[d1];
    float p0 = -INFINITY, p1 = -INFINITY;

    for (int dt = -1; dt <= 1; ++dt) {
        int frame = 2 * f + dt;
        frame = frame < 0 ? 0 : (frame > 14 ? 14 : frame);
        const float* src = input + ((size_t)(b * TT + frame)) * NN * 3;

        // thread t owns consecutive points [8t, 8t+8)
        float px[8], py[8], pz[8];
        const float4* s4 = (const float4*)(src + tid * 24);
        float4 v0 = s4[0], v1 = s4[1], v2 = s4[2], v3 = s4[3], v4 = s4[4], v5 = s4[5];
        px[0] = v0.x; py[0] = v0.y; pz[0] = v0.z;
        px[1] = v0.w; py[1] = v1.x; pz[1] = v1.y;
        px[2] = v1.z; py[2] = v1.w; pz[2] = v2.x;
        px[3] = v2.y; py[3] = v2.z; pz[3] = v2.w;
        px[4] = v3.x; py[4] = v3.y; pz[4] = v3.z;
        px[5] = v3.w; py[5] = v4.x; pz[5] = v4.y;
        px[6] = v4.z; py[6] = v4.w; pz[6] = v5.x;
        px[7] = v5.y; py[7] = v5.z; pz[7] = v5.w;

        unsigned hit = 0; int cnt = 0;
#pragma unroll
        for (int j = 0; j < 8; ++j) {
            float dx = ax - px[j], dy = ay - py[j], dz = az - pz[j];
            float d2 = __fadd_rn(__fadd_rn(__fmul_rn(dx, dx), __fmul_rn(dy, dy)),
                                 __fmul_rn(dz, dz));
            if (d2 < R2) { hit |= 1u << j; cnt++; }
        }
        // wave inclusive scan of cnt
        int s = cnt;
#pragma unroll
        for (int off = 1; off < 64; off <<= 1) {
            int o = __shfl_up(s, off);
            if (lane >= off) s += o;
        }
        if (lane == 63) swtot[w] = s;
        __syncthreads();
        int wavebase = 0, total = 0;
#pragma unroll
        for (int ww = 0; ww < 4; ++ww) {
            int t2 = swtot[ww];
            total += t2;
            if (ww < w) wavebase += t2;
        }
        int r = wavebase + s - cnt;   // exclusive global rank of this thread's first hit
#pragma unroll
        for (int j = 0; j < 8; ++j) {
            if (hit & (1u << j)) {
                if (r < KH) { hx[r] = px[j]; hy[r] = py[j]; hz[r] = pz[j]; }
                r++;
            }
        }
        if (total == 0 && tid == 0) { hx[0] = px[0]; hy[0] = py[0]; hz[0] = pz[0]; }
        __syncthreads();

        int nh = (total == 0) ? 1 : (total < KH ? total : KH);
        float dtf = (float)dt;
        for (int k = 0; k < nh; ++k) {
            float gx = hx[k], gy = hy[k], gz = hz[k];
            float dx = gx - ax, dy = gy - ay, dz = gz - az;
            float v0d = dx * wd0.x + dy * wd0.y + dz * wd0.z + dtf * wd0.w + gz * wf0;
            float v1d = dx * wd1.x + dy * wd1.y + dz * wd1.z + dtf * wd1.w + gz * wf1;
            p0 = fmaxf(p0, v0d);
            p1 = fmaxf(p1, v1d);
        }
        __syncthreads();   // WAR on hx/hy/hz/swtot before next dt
    }

    // epilogue: positional linear + bias + relu, float32 store
    float4 wp0 = ((const float4*)W_pos)[d0];
    float4 wp1 = ((const float4*)W_pos)[d1];
    float tv = (float)(f + 1);
    float pos0 = ax * wp0.x + ay * wp0.y + az * wp0.z + tv * wp0.w + b_pos[d0];
    float pos1 = ax * wp1.x + ay * wp1.y + az * wp1.z + tv * wp1.w + b_pos[d1];
    float o0 = fmaxf(pos0 + p0, 0.0f);
    float o1 = fmaxf(pos1 + p1, 0.0f);
    size_t row = ((size_t)b * (TO * MM) + f * MM + m) * DIMD;
    outp[row + d0] = o0;
    outp[row + d1] = o1;
}

extern "C" void kernel_launch(void* const* d_in, const int* in_sizes, int n_in,
                              void* d_out, int out_size, void* d_ws, size_t ws_size,
                              hipStream_t stream) {
    const float* input = (const float*)d_in[0];
    const float* W_d   = (const float*)d_in[1];
    const float* W_f   = (const float*)d_in[2];
    const float* W_pos = (const float*)d_in[3];
    const float* b_pos = (const float*)d_in[4];
    float* anchor = (float*)d_ws;   // 16*64*3 floats = 12 KB

    fps_kernel<<<16, 256, 0, stream>>>(input, anchor);
    encode_kernel<<<1024, 256, 0, stream>>>(input, W_d, W_f, W_pos, b_pos, anchor,
                                            (float*)d_out);
}